// Round 6
// baseline (428.917 us; speedup 1.0000x reference)
//
#include <hip/hip_runtime.h>
#include <stdint.h>

#define B_ 4
#define N_ 16384
#define D_ 512
#define S_ 512

typedef __attribute__((ext_vector_type(8))) short bf16x8;
typedef __attribute__((ext_vector_type(4))) float f32x4;

__device__ __forceinline__ float bf2f(unsigned short u) {
  union { unsigned int i; float f; } v; v.i = ((unsigned int)u) << 16; return v.f;
}
__device__ __forceinline__ unsigned short f2bf(float f) {
  unsigned int x = __float_as_uint(f);
  return (unsigned short)((x + 0x7FFFu + ((x >> 16) & 1u)) >> 16);
}
__device__ __forceinline__ float ldf(const void* p, long i, bool f32) {
  return f32 ? ((const float*)p)[i] : bf2f(((const unsigned short*)p)[i]);
}
__device__ __forceinline__ void gl_lds16(void* lds_base, const void* g) {
  __builtin_amdgcn_global_load_lds(
      (const __attribute__((address_space(1))) unsigned int*)g,
      (__attribute__((address_space(3))) unsigned int*)lds_base,
      16, 0, 0);
}

// Per-block inline dtype classify (flag = input is f32); see round-2 notes.
__device__ __forceinline__ bool classify_f32(const unsigned short* x, int* cnt) {
  int c = 0;
#pragma unroll
  for (int i = 0; i < 8; i++) {
    unsigned short w = x[threadIdx.x * 8 + i];
    int e = (w >> 7) & 0xFF;
    if (e == 0 || (e >= 100 && e <= 140)) c++;
  }
  cnt[threadIdx.x] = c;
  __syncthreads();
  for (int s = 128; s > 0; s >>= 1) {
    if ((int)threadIdx.x < s) cnt[threadIdx.x] += cnt[threadIdx.x + s];
    __syncthreads();
  }
  bool f32 = cnt[0] < 1843;
  __syncthreads();
  return f32;
}

__device__ __forceinline__ bool jx_is_i64(const int* jx32) { return jx32[N_ - 1] == 0; }
__device__ __forceinline__ int seg_id(const int* jx32, int n, bool i64) {
  return i64 ? jx32[2 * n] : jx32[n];
}

// ---------------------------------------------------------------------------
// prep_all: [0,16384) x -> bf16 (xb lives in d_out, dead before gather);
// [16384,19462) weights/biases (Wfg col-INTERLEAVED: row 2d=Wf[d], 2d+1=Wg[d]).
__global__ __launch_bounds__(256)
void prep_all(const void* __restrict__ x, const int* __restrict__ jx,
              const void* __restrict__ Wf, const void* __restrict__ bfv,
              const void* __restrict__ Wg, const void* __restrict__ bgv,
              const void* __restrict__ Wh, const void* __restrict__ bhv,
              unsigned short* __restrict__ xb, unsigned short* __restrict__ Wfg,
              unsigned short* __restrict__ biasfg, unsigned short* __restrict__ Whb,
              unsigned short* __restrict__ bhb) {
  const int blk = blockIdx.x, tid = threadIdx.x;
  __shared__ int cnt[256];
  const bool f32 = classify_f32((const unsigned short*)x, cnt);
  if (blk < 16384) {
    const size_t i0 = ((size_t)blk * 256 + tid) * 8;
    bf16x8 v;
    if (f32) {
      const float4* p = (const float4*)((const float*)x + i0);
      float4 a = p[0], b = p[1];
      v[0]=f2bf(a.x); v[1]=f2bf(a.y); v[2]=f2bf(a.z); v[3]=f2bf(a.w);
      v[4]=f2bf(b.x); v[5]=f2bf(b.y); v[6]=f2bf(b.z); v[7]=f2bf(b.w);
    } else {
      v = *(const bf16x8*)((const unsigned short*)x + i0);
    }
    *(bf16x8*)(xb + i0) = v;
  } else {
    int idx = (blk - 16384) * 256 + tid;
    if (idx < 524288) {
      int e = idx >> 9, dcol = idx & 511;
      int drow = e >> 1;
      float v = (e & 1) ? ldf(Wg, (long)drow * 512 + dcol, f32)
                        : ldf(Wf, (long)drow * 512 + dcol, f32);
      Wfg[idx] = f2bf(v);
    } else if (idx < 786432) {
      Whb[idx - 524288] = f2bf(ldf(Wh, idx - 524288, f32));
    } else if (idx < 787456) {
      int j = idx - 786432;
      biasfg[j] = f2bf((j & 1) ? ldf(bgv, j >> 1, f32) : ldf(bfv, j >> 1, f32));
    } else if (idx < 787968) {
      bhb[idx - 787456] = f2bf(ldf(bhv, idx - 787456, f32));
    }
  }
}

// ---------------------------------------------------------------------------
// Fused fg GEMM + segment reduction. Tile 128x128 over [65536 rows x 1024
// interleaved cols]. Epilogue: pair (f,g) via shfl_xor(1), e=exp(g), then
// per-pass (j=0..3) LDS staging of (f*e, e) float2 [128 rows x 16 d-slots]
// reusing the As/Bs LDS, run-compressed atomicAdd into nd[b,s,d] (float2).
#define BK 32

__global__ __launch_bounds__(256, 2)
void gemm_fg_fused(const unsigned short* __restrict__ A,
                   const unsigned short* __restrict__ Bm,
                   const unsigned short* __restrict__ bias,
                   const int* __restrict__ jx,
                   float* __restrict__ nd) {
  __shared__ __align__(16) char smem[16384];
  unsigned short* As = (unsigned short*)smem;             // 8 KB
  unsigned short* Bs = (unsigned short*)(smem + 8192);    // 8 KB
  float2* red = (float2*)smem;                            // 16 KB (epilogue)

  const int L = blockIdx.x;
  const int xcd = L & 7, local = L >> 3;
  const int tm = xcd * 64 + local / 8;     // tilesM=512, tilesM/8=64
  const int tn = local % 8;                // tilesN=8
  const int m0 = tm * 128, n0 = tn * 128;
  const int b = m0 >> 14;                  // 16384 rows per batch
  const int nbase = m0 & (N_ - 1);

  const int tid  = threadIdx.x;
  const int w    = tid >> 6;
  const int lane = tid & 63;
  const int wm   = w >> 1, wn = w & 1;
  const int l15  = lane & 15, l4 = lane >> 4;
  const int srow = lane >> 2;
  const int scol = (lane & 3) * 8;

  f32x4 acc[4][4];
#pragma unroll
  for (int i = 0; i < 4; i++)
#pragma unroll
    for (int j = 0; j < 4; j++) acc[i][j] = (f32x4){0.f, 0.f, 0.f, 0.f};

  for (int kt = 0; kt < 512; kt += BK) {
    __syncthreads();
#pragma unroll
    for (int r = 0; r < 2; r++) {
      const int rb = (r * 4 + w) * 16;
      gl_lds16(&As[rb * BK], A + (size_t)(m0 + rb + srow) * 512 + kt + scol);
      gl_lds16(&Bs[rb * BK], Bm + (size_t)(n0 + rb + srow) * 512 + kt + scol);
    }
    __syncthreads();

    bf16x8 a[4], bb[4];
#pragma unroll
    for (int i = 0; i < 4; i++)
      a[i] = *(const bf16x8*)&As[(wm * 64 + i * 16 + l15) * BK + l4 * 8];
#pragma unroll
    for (int j = 0; j < 4; j++)
      bb[j] = *(const bf16x8*)&Bs[(wn * 64 + j * 16 + l15) * BK + l4 * 8];
#pragma unroll
    for (int i = 0; i < 4; i++)
#pragma unroll
      for (int j = 0; j < 4; j++)
        acc[i][j] = __builtin_amdgcn_mfma_f32_16x16x32_bf16(a[i], bb[j], acc[i][j], 0, 0, 0);
  }

  // ---- fused epilogue ----
  const bool i64 = jx_is_i64(jx);
  const bool evenlane = (l15 & 1) == 0;
  const int slot_w = wn * 8 + (l15 >> 1);   // d-slot this lane writes
  for (int j = 0; j < 4; j++) {
    __syncthreads();   // LDS free (prev pass readers / K-loop done)
    const int col = n0 + wn * 64 + j * 16 + l15;
    const float bv = bf2f(bias[col]);
#pragma unroll
    for (int i = 0; i < 4; i++) {
#pragma unroll
      for (int r = 0; r < 4; r++) {
        const float val = acc[i][j][r] + bv;        // f or g (+bias)
        const float partner = __shfl_xor(val, 1);   // pair f<->g
        if (evenlane) {
          const float e = __expf(partner);          // partner = g
          const int row = wm * 64 + i * 16 + l4 * 4 + r;
          red[row * 16 + slot_w] = make_float2(val * e, e);
        }
      }
    }
    __syncthreads();
    // reduction: 128 threads, slot = t&15 (d), chunk = t>>4 (16 rows each)
    if (tid < 128) {
      const int slot = tid & 15, chunk = tid >> 4;
      const int dg = (n0 >> 1) + (slot >> 3) * 32 + j * 8 + (slot & 7);
      const int rbase = chunk * 16;
      float nsum = 0.f, dsum = 0.f;
      int cur = seg_id(jx, nbase + rbase, i64);
      for (int k = 0; k < 16; k++) {
        const int sg = seg_id(jx, nbase + rbase + k, i64);
        const float2 v = red[(rbase + k) * 16 + slot];
        if (sg != cur) {
          float* t = nd + (((size_t)(b * S_ + cur)) * 512 + dg) * 2;
          atomicAdd(t, nsum); atomicAdd(t + 1, dsum);
          nsum = 0.f; dsum = 0.f; cur = sg;
        }
        nsum += v.x; dsum += v.y;
      }
      float* t = nd + (((size_t)(b * S_ + cur)) * 512 + dg) * 2;
      atomicAdd(t, nsum); atomicAdd(t + 1, dsum);
    }
  }
}

// ---------------------------------------------------------------------------
// y[b,s,d] = num/den (0 if empty segment), bf16 out. 2 elems/thread.
__global__ __launch_bounds__(256)
void y_div(const float* __restrict__ nd, unsigned short* __restrict__ y) {
  const size_t i0 = ((size_t)blockIdx.x * 256 + threadIdx.x) * 2;
  const float4 v = *(const float4*)(nd + i0 * 2);  // (n0,d0,n1,d1)
  unsigned int o = (unsigned int)f2bf(v.y > 0.f ? v.x / v.y : 0.f)
                 | ((unsigned int)f2bf(v.w > 0.f ? v.z / v.w : 0.f) << 16);
  *(unsigned int*)(y + i0) = o;
}

// ---------------------------------------------------------------------------
// Generic bf16 GEMM (for hy): C[m,e] = sum_k A[m,k]*B[e,k] + bias[e].
__global__ __launch_bounds__(256, 2)
void gemm_bt(const unsigned short* __restrict__ A, const unsigned short* __restrict__ Bm,
             const unsigned short* __restrict__ bias, unsigned short* __restrict__ C,
             int E, int Kdim, int tilesM, int tilesN) {
  __shared__ __align__(16) unsigned short As[128 * BK];
  __shared__ __align__(16) unsigned short Bs[128 * BK];
  const int L = blockIdx.x;
  const int xcd = L & 7, local = L >> 3;
  const int tm = xcd * (tilesM >> 3) + local / tilesN;
  const int tn = local % tilesN;
  const int m0 = tm * 128, n0 = tn * 128;
  const int tid  = threadIdx.x;
  const int w    = tid >> 6;
  const int lane = tid & 63;
  const int wm   = w >> 1, wn = w & 1;
  const int l15  = lane & 15, l4 = lane >> 4;
  const int srow = lane >> 2, scol = (lane & 3) * 8;

  f32x4 acc[4][4];
#pragma unroll
  for (int i = 0; i < 4; i++)
#pragma unroll
    for (int j = 0; j < 4; j++) acc[i][j] = (f32x4){0.f, 0.f, 0.f, 0.f};

  for (int kt = 0; kt < Kdim; kt += BK) {
    __syncthreads();
#pragma unroll
    for (int r = 0; r < 2; r++) {
      const int rb = (r * 4 + w) * 16;
      gl_lds16(&As[rb * BK], A + (size_t)(m0 + rb + srow) * Kdim + kt + scol);
      gl_lds16(&Bs[rb * BK], Bm + (size_t)(n0 + rb + srow) * Kdim + kt + scol);
    }
    __syncthreads();
    bf16x8 a[4], bb[4];
#pragma unroll
    for (int i = 0; i < 4; i++)
      a[i] = *(const bf16x8*)&As[(wm * 64 + i * 16 + l15) * BK + l4 * 8];
#pragma unroll
    for (int j = 0; j < 4; j++)
      bb[j] = *(const bf16x8*)&Bs[(wn * 64 + j * 16 + l15) * BK + l4 * 8];
#pragma unroll
    for (int i = 0; i < 4; i++)
#pragma unroll
      for (int j = 0; j < 4; j++)
        acc[i][j] = __builtin_amdgcn_mfma_f32_16x16x32_bf16(a[i], bb[j], acc[i][j], 0, 0, 0);
  }
#pragma unroll
  for (int j = 0; j < 4; j++) {
    const int col = n0 + wn * 64 + j * 16 + l15;
    const float bv = bf2f(bias[col]);
#pragma unroll
    for (int i = 0; i < 4; i++) {
      const int rowb = m0 + wm * 64 + i * 16 + l4 * 4;
#pragma unroll
      for (int r = 0; r < 4; r++)
        C[(size_t)(rowb + r) * E + col] = f2bf(acc[i][j][r] + bv);
    }
  }
}

// ---------------------------------------------------------------------------
// out[b,n,:] = hy[b*S + jx[n], :]; one wave per row; f32 path uses float4 x2.
__global__ __launch_bounds__(256)
void gather_out(const unsigned short* __restrict__ hy, const int* __restrict__ jx,
                void* __restrict__ out, const void* __restrict__ x) {
  __shared__ int cnt[256];
  const bool f32 = classify_f32((const unsigned short*)x, cnt);
  const int gid  = blockIdx.x * 256 + threadIdx.x;
  const int wid  = gid >> 6;
  const int lane = gid & 63;
  const int b = wid >> 14;
  const int n = wid & (N_ - 1);
  const bool i64 = jx_is_i64(jx);
  const int s = seg_id(jx, n, i64);
  const bf16x8 v = *(const bf16x8*)(hy + (size_t)(b * S_ + s) * 512 + lane * 8);
  if (f32) {
    float* dst = (float*)out + (size_t)wid * 512 + lane * 8;
    float4 lo, hi;
    lo.x=bf2f((unsigned short)v[0]); lo.y=bf2f((unsigned short)v[1]);
    lo.z=bf2f((unsigned short)v[2]); lo.w=bf2f((unsigned short)v[3]);
    hi.x=bf2f((unsigned short)v[4]); hi.y=bf2f((unsigned short)v[5]);
    hi.z=bf2f((unsigned short)v[6]); hi.w=bf2f((unsigned short)v[7]);
    *(float4*)dst = lo;
    *(float4*)(dst + 4) = hi;
  } else {
    *(bf16x8*)((unsigned short*)out + (size_t)wid * 512 + lane * 8) = v;
  }
}

// ---------------------------------------------------------------------------
extern "C" void kernel_launch(void* const* d_in, const int* in_sizes, int n_in,
                              void* d_out, int out_size, void* d_ws, size_t ws_size,
                              hipStream_t stream) {
  const void* x  = d_in[0];
  const int* jx  = (const int*)d_in[1];
  const void* Wf = d_in[3];
  const void* bf = d_in[4];
  const void* Wg = d_in[5];
  const void* bg = d_in[6];
  const void* Wh = d_in[7];
  const void* bh = d_in[8];

  // ws footprint kept <= 16 MB (round-5 post-mortem: ws_size < 80 MB; a 64 MB
  // xb at offset 16 MB ran OOB and corrupted the harness's pristine inputs).
  char* ws = (char*)d_ws;
  unsigned short* biasfg = (unsigned short*)(ws + 8192);
  unsigned short* bhb    = (unsigned short*)(ws + 16384);
  unsigned short* Wfg    = (unsigned short*)(ws + 32768);      // 1 MB
  unsigned short* Whb    = (unsigned short*)(ws + 1081344);    // 0.5 MB
  unsigned short* y_ws   = (unsigned short*)(ws + 1605632);    // 2 MB
  unsigned short* hy_ws  = (unsigned short*)(ws + 3702784);    // 2 MB
  float*          nd     = (float*)(ws + 8388608);             // 8 MB (num,den)
  // xb (64 MB bf16 x) lives in d_out (128 MB, f32 out): dead before gather.
  unsigned short* xb     = (unsigned short*)d_out;

  hipMemsetAsync(nd, 0, (size_t)B_ * S_ * D_ * 2 * sizeof(float), stream);
  prep_all<<<19462, 256, 0, stream>>>(x, jx, Wf, bf, Wg, bg, Wh, bh,
                                      xb, Wfg, biasfg, Whb, bhb);
  gemm_fg_fused<<<4096, 256, 0, stream>>>(xb, Wfg, biasfg, jx, nd);
  y_div<<<2048, 256, 0, stream>>>(nd, y_ws);
  gemm_bt<<<64, 256, 0, stream>>>(y_ws, Whb, bhb, hy_ws, 512, 512, 16, 4);
  gather_out<<<16384, 256, 0, stream>>>(hy_ws, jx, d_out, x);
}

// Round 7
// 417.056 us; speedup vs baseline: 1.0284x; 1.0284x over previous
//
#include <hip/hip_runtime.h>
#include <stdint.h>

#define B_ 4
#define N_ 16384
#define D_ 512
#define S_ 512

typedef __attribute__((ext_vector_type(8))) short bf16x8;
typedef __attribute__((ext_vector_type(4))) float f32x4;

__device__ __forceinline__ float bf2f(unsigned short u) {
  union { unsigned int i; float f; } v; v.i = ((unsigned int)u) << 16; return v.f;
}
__device__ __forceinline__ unsigned short f2bf(float f) {
  unsigned int x = __float_as_uint(f);
  return (unsigned short)((x + 0x7FFFu + ((x >> 16) & 1u)) >> 16);
}
__device__ __forceinline__ float ldf(const void* p, long i, bool f32) {
  return f32 ? ((const float*)p)[i] : bf2f(((const unsigned short*)p)[i]);
}
__device__ __forceinline__ void gl_lds16(void* lds_base, const void* g) {
  __builtin_amdgcn_global_load_lds(
      (const __attribute__((address_space(1))) unsigned int*)g,
      (__attribute__((address_space(3))) unsigned int*)lds_base,
      16, 0, 0);
}

__device__ __forceinline__ bool jx_is_i64(const int* jx32) { return jx32[N_ - 1] == 0; }
__device__ __forceinline__ int seg_id(const int* jx32, int n, bool i64) {
  return i64 ? jx32[2 * n] : jx32[n];
}

// ---------------------------------------------------------------------------
// k0: classify x dtype (flag=1 -> f32) + segment bounds. 3 blocks; classify is
// computed redundantly per block (idempotent write), bounds split across blocks.
__global__ __launch_bounds__(256)
void k0_flag_bounds(const unsigned short* __restrict__ x, const int* __restrict__ jx,
                    int* __restrict__ flag, int* __restrict__ segst) {
  __shared__ int cnt[256];
  int c = 0;
#pragma unroll
  for (int i = 0; i < 8; i++) {
    unsigned short w = x[threadIdx.x * 8 + i];
    int e = (w >> 7) & 0xFF;
    if (e == 0 || (e >= 100 && e <= 140)) c++;
  }
  cnt[threadIdx.x] = c;
  __syncthreads();
  for (int s = 128; s > 0; s >>= 1) {
    if ((int)threadIdx.x < s) cnt[threadIdx.x] += cnt[threadIdx.x + s];
    __syncthreads();
  }
  if (threadIdx.x == 0) flag[0] = (cnt[0] < 1843) ? 1 : 0;

  const int s = blockIdx.x * 256 + threadIdx.x;
  if (s > S_) return;
  const bool i64 = jx_is_i64(jx);
  int lo = 0, hi = N_;
  while (lo < hi) {
    int mid = (lo + hi) >> 1;
    if (seg_id(jx, mid, i64) < s) lo = mid + 1; else hi = mid;
  }
  segst[s] = lo;
}

// ---------------------------------------------------------------------------
// prep_w: weights/biases -> bf16. Wfg = [Wf; Wg] stacked (1024 x 512), biasfg
// = [bf | bg], Whb, bhb. 787968 elems / 256 = 3078 blocks.
__global__ __launch_bounds__(256)
void prep_w(const void* __restrict__ Wf, const void* __restrict__ bfv,
            const void* __restrict__ Wg, const void* __restrict__ bgv,
            const void* __restrict__ Wh, const void* __restrict__ bhv,
            const int* __restrict__ flag,
            unsigned short* __restrict__ Wfg, unsigned short* __restrict__ biasfg,
            unsigned short* __restrict__ Whb, unsigned short* __restrict__ bhb) {
  const bool f32 = flag[0] != 0;
  int idx = blockIdx.x * 256 + threadIdx.x;
  if (idx < 524288) {
    int e = idx >> 9, d = idx & 511;
    float v = (e < 512) ? ldf(Wf, (long)e * 512 + d, f32)
                        : ldf(Wg, (long)(e - 512) * 512 + d, f32);
    Wfg[idx] = f2bf(v);
  } else if (idx < 786432) {
    Whb[idx - 524288] = f2bf(ldf(Wh, idx - 524288, f32));
  } else if (idx < 787456) {
    int j = idx - 786432;
    biasfg[j] = f2bf(j < 512 ? ldf(bfv, j, f32) : ldf(bgv, j - 512, f32));
  } else if (idx < 787968) {
    bhb[idx - 787456] = f2bf(ldf(bhv, idx - 787456, f32));
  }
}

// ---------------------------------------------------------------------------
// fg GEMM reading x DIRECTLY (f32 or bf16, runtime flag): A-tile staged with
// in-register f32->bf16 conversion (f32 path) or global_load_lds (bf16 path);
// B (weights, bf16) always global_load_lds. 128x128 tile, BK=32, 4 waves 2x2,
// 4x4 mfma 16x16x32. XCD swizzle: consecutive blocks within an XCD share the
// A row-tile (8 col-tiles) -> A fetched ~once from HBM.
#define BK 32

__global__ __launch_bounds__(256, 2)
void gemm_fg(const void* __restrict__ A, const unsigned short* __restrict__ Bm,
             const unsigned short* __restrict__ bias, const int* __restrict__ flag,
             unsigned short* __restrict__ Cf, unsigned short* __restrict__ Cg) {
  __shared__ __align__(16) unsigned short As[128 * BK];
  __shared__ __align__(16) unsigned short Bs[128 * BK];
  const bool af32 = flag[0] != 0;
  const int L = blockIdx.x;
  const int xcd = L & 7, local = L >> 3;
  const int tm = xcd * 64 + local / 8;     // tilesM=512 -> 64 per XCD
  const int tn = local % 8;                // tilesN=8
  const int m0 = tm * 128, n0 = tn * 128;

  const int tid  = threadIdx.x;
  const int w    = tid >> 6;
  const int lane = tid & 63;
  const int wm   = w >> 1, wn = w & 1;
  const int l15  = lane & 15, l4 = lane >> 4;
  const int srow = lane >> 2;        // gl_lds staging: 4 lanes/row
  const int scol = (lane & 3) * 8;
  const int arow = tid >> 1;         // f32 A staging: 2 threads/row
  const int ak0  = (tid & 1) * 16;

  f32x4 acc[4][4];
#pragma unroll
  for (int i = 0; i < 4; i++)
#pragma unroll
    for (int j = 0; j < 4; j++) acc[i][j] = (f32x4){0.f, 0.f, 0.f, 0.f};

  for (int kt = 0; kt < 512; kt += BK) {
    __syncthreads();
    // stage B via async 16B global->LDS
#pragma unroll
    for (int r = 0; r < 2; r++) {
      const int rb = (r * 4 + w) * 16;
      gl_lds16(&Bs[rb * BK], Bm + (size_t)(n0 + rb + srow) * 512 + kt + scol);
    }
    // stage A
    if (af32) {
      const float4* ap = (const float4*)((const float*)A +
                          (size_t)(m0 + arow) * 512 + kt + ak0);
      float4 a0 = ap[0], a1 = ap[1], a2 = ap[2], a3 = ap[3];
      bf16x8 v0, v1;
      v0[0]=f2bf(a0.x); v0[1]=f2bf(a0.y); v0[2]=f2bf(a0.z); v0[3]=f2bf(a0.w);
      v0[4]=f2bf(a1.x); v0[5]=f2bf(a1.y); v0[6]=f2bf(a1.z); v0[7]=f2bf(a1.w);
      v1[0]=f2bf(a2.x); v1[1]=f2bf(a2.y); v1[2]=f2bf(a2.z); v1[3]=f2bf(a2.w);
      v1[4]=f2bf(a3.x); v1[5]=f2bf(a3.y); v1[6]=f2bf(a3.z); v1[7]=f2bf(a3.w);
      *(bf16x8*)&As[arow * BK + ak0]     = v0;
      *(bf16x8*)&As[arow * BK + ak0 + 8] = v1;
    } else {
#pragma unroll
      for (int r = 0; r < 2; r++) {
        const int rb = (r * 4 + w) * 16;
        gl_lds16(&As[rb * BK],
                 (const unsigned short*)A + (size_t)(m0 + rb + srow) * 512 + kt + scol);
      }
    }
    __syncthreads();

    bf16x8 a[4], bb[4];
#pragma unroll
    for (int i = 0; i < 4; i++)
      a[i] = *(const bf16x8*)&As[(wm * 64 + i * 16 + l15) * BK + l4 * 8];
#pragma unroll
    for (int j = 0; j < 4; j++)
      bb[j] = *(const bf16x8*)&Bs[(wn * 64 + j * 16 + l15) * BK + l4 * 8];
#pragma unroll
    for (int i = 0; i < 4; i++)
#pragma unroll
      for (int j = 0; j < 4; j++)
        acc[i][j] = __builtin_amdgcn_mfma_f32_16x16x32_bf16(a[i], bb[j], acc[i][j], 0, 0, 0);
  }

  // epilogue: C/D layout col=lane&15, row=(lane>>4)*4+r; split f (col<512) / g
#pragma unroll
  for (int j = 0; j < 4; j++) {
    const int col = n0 + wn * 64 + j * 16 + l15;
    const float bv = bf2f(bias[col]);
    unsigned short* base = (col < 512) ? Cf : Cg;
    const int cc = col & 511;
#pragma unroll
    for (int i = 0; i < 4; i++) {
      const int rowb = m0 + wm * 64 + i * 16 + l4 * 4;
#pragma unroll
      for (int r = 0; r < 4; r++)
        base[(size_t)(rowb + r) * 512 + cc] = f2bf(acc[i][j][r] + bv);
    }
  }
}

// ---------------------------------------------------------------------------
// Online segment softmax + weighted sum; 2 segments/block, 4 cols/thread.
// |g| < ~7 so no max subtraction (f32 exp exact enough).
__global__ __launch_bounds__(256)
void seg_softmax(const unsigned short* __restrict__ f, const unsigned short* __restrict__ g,
                 const int* __restrict__ segst, unsigned short* __restrict__ y) {
  const int s = blockIdx.x * 2 + (threadIdx.x >> 7);
  const int b = blockIdx.y;
  const int d0 = (threadIdx.x & 127) * 4;
  const int st = segst[s], en = segst[s + 1];
  float den0=0.f, den1=0.f, den2=0.f, den3=0.f;
  float y0=0.f, y1=0.f, y2=0.f, y3=0.f;
  for (int n = st; n < en; n++) {
    const size_t off = (size_t)(b * N_ + n) * 512 + d0;
    const uint2 fp = *(const uint2*)(f + off);
    const uint2 gp = *(const uint2*)(g + off);
    const float f0 = bf2f((unsigned short)fp.x), f1 = bf2f((unsigned short)(fp.x >> 16));
    const float f2 = bf2f((unsigned short)fp.y), f3 = bf2f((unsigned short)(fp.y >> 16));
    const float g0 = bf2f((unsigned short)gp.x), g1 = bf2f((unsigned short)(gp.x >> 16));
    const float g2 = bf2f((unsigned short)gp.y), g3 = bf2f((unsigned short)(gp.y >> 16));
    const float e0 = __expf(g0), e1 = __expf(g1), e2 = __expf(g2), e3 = __expf(g3);
    den0 += e0; den1 += e1; den2 += e2; den3 += e3;
    y0 += f0 * e0; y1 += f1 * e1; y2 += f2 * e2; y3 += f3 * e3;
  }
  uint2 o;
  if (en > st) {
    o.x = (unsigned int)f2bf(y0 / den0) | ((unsigned int)f2bf(y1 / den1) << 16);
    o.y = (unsigned int)f2bf(y2 / den2) | ((unsigned int)f2bf(y3 / den3) << 16);
  } else { o.x = 0u; o.y = 0u; }
  *(uint2*)(y + (size_t)(b * S_ + s) * 512 + d0) = o;
}

// ---------------------------------------------------------------------------
// hy GEMM: hy[m,c] = sum_k y[m,k]*Whb[c,k] + bhb[c]; 64x64 tiles, 256 blocks.
__global__ __launch_bounds__(256)
void gemm_hy(const unsigned short* __restrict__ y, const unsigned short* __restrict__ Whb,
             const unsigned short* __restrict__ bhb, unsigned short* __restrict__ hy) {
  __shared__ __align__(16) unsigned short As[64 * 32];
  __shared__ __align__(16) unsigned short Bs[64 * 32];
  const int tid = threadIdx.x;
  const int w = tid >> 6, lane = tid & 63;
  const int l15 = lane & 15, l4 = lane >> 4;
  const int m0 = (blockIdx.x >> 3) * 64, c0 = (blockIdx.x & 7) * 64;
  const int srow = lane >> 2, scol = (lane & 3) * 8;

  f32x4 acc[4];
#pragma unroll
  for (int j = 0; j < 4; j++) acc[j] = (f32x4){0.f, 0.f, 0.f, 0.f};

  for (int kt = 0; kt < 512; kt += 32) {
    __syncthreads();
    gl_lds16(&As[(w * 16) * 32], y   + (size_t)(m0 + w * 16 + srow) * 512 + kt + scol);
    gl_lds16(&Bs[(w * 16) * 32], Whb + (size_t)(c0 + w * 16 + srow) * 512 + kt + scol);
    __syncthreads();
    bf16x8 a = *(const bf16x8*)&As[(w * 16 + l15) * 32 + l4 * 8];
#pragma unroll
    for (int j = 0; j < 4; j++) {
      bf16x8 bb = *(const bf16x8*)&Bs[(j * 16 + l15) * 32 + l4 * 8];
      acc[j] = __builtin_amdgcn_mfma_f32_16x16x32_bf16(a, bb, acc[j], 0, 0, 0);
    }
  }
#pragma unroll
  for (int j = 0; j < 4; j++) {
    const float bv = bf2f(bhb[c0 + j * 16 + l15]);
#pragma unroll
    for (int r = 0; r < 4; r++)
      hy[(size_t)(m0 + w * 16 + l4 * 4 + r) * 512 + c0 + j * 16 + l15] =
          f2bf(acc[j][r] + bv);
  }
}

// ---------------------------------------------------------------------------
// out[b,n,:] = hy[b*S + jx[n], :]; one wave per row, vectorized stores.
__global__ __launch_bounds__(256)
void gather_out(const unsigned short* __restrict__ hy, const int* __restrict__ jx,
                void* __restrict__ out, const int* __restrict__ flag) {
  const bool f32 = flag[0] != 0;
  const int gid  = blockIdx.x * 256 + threadIdx.x;
  const int wid  = gid >> 6;
  const int lane = gid & 63;
  const int b = wid >> 14;
  const int n = wid & (N_ - 1);
  const bool i64 = jx_is_i64(jx);
  const int s = seg_id(jx, n, i64);
  const bf16x8 v = *(const bf16x8*)(hy + (size_t)(b * S_ + s) * 512 + lane * 8);
  if (f32) {
    float* dst = (float*)out + (size_t)wid * 512 + lane * 8;
    float4 lo, hi;
    lo.x=bf2f((unsigned short)v[0]); lo.y=bf2f((unsigned short)v[1]);
    lo.z=bf2f((unsigned short)v[2]); lo.w=bf2f((unsigned short)v[3]);
    hi.x=bf2f((unsigned short)v[4]); hi.y=bf2f((unsigned short)v[5]);
    hi.z=bf2f((unsigned short)v[6]); hi.w=bf2f((unsigned short)v[7]);
    *(float4*)dst = lo;
    *(float4*)(dst + 4) = hi;
  } else {
    *(bf16x8*)((unsigned short*)out + (size_t)wid * 512 + lane * 8) = v;
  }
}

// ---------------------------------------------------------------------------
extern "C" void kernel_launch(void* const* d_in, const int* in_sizes, int n_in,
                              void* d_out, int out_size, void* d_ws, size_t ws_size,
                              hipStream_t stream) {
  const void* x  = d_in[0];
  const int* jx  = (const int*)d_in[1];
  const void* Wf = d_in[3];
  const void* bf = d_in[4];
  const void* Wg = d_in[5];
  const void* bg = d_in[6];
  const void* Wh = d_in[7];
  const void* bh = d_in[8];

  // ws footprint < 8 MB (ws_size known >= 16 MB safe; round-5 lesson: stay small)
  char* ws = (char*)d_ws;
  int* flag              = (int*)(ws + 0);
  int* segst             = (int*)(ws + 4096);
  unsigned short* biasfg = (unsigned short*)(ws + 8192);
  unsigned short* bhb    = (unsigned short*)(ws + 16384);
  unsigned short* Wfg    = (unsigned short*)(ws + 32768);      // 1 MB
  unsigned short* Whb    = (unsigned short*)(ws + 1081344);    // 0.5 MB
  unsigned short* y_ws   = (unsigned short*)(ws + 1605632);    // 2 MB
  unsigned short* hy_ws  = (unsigned short*)(ws + 3702784);    // 2 MB
  // fbuf/gbuf (2 x 64 MB bf16) live in d_out (128 MB f32); dead before gather.
  unsigned short* fbuf   = (unsigned short*)d_out;
  unsigned short* gbuf   = (unsigned short*)d_out + (size_t)B_ * N_ * D_;

  k0_flag_bounds<<<3, 256, 0, stream>>>((const unsigned short*)x, jx, flag, segst);
  prep_w<<<3078, 256, 0, stream>>>(Wf, bf, Wg, bg, Wh, bh, flag,
                                   Wfg, biasfg, Whb, bhb);
  gemm_fg<<<4096, 256, 0, stream>>>(x, Wfg, biasfg, flag, fbuf, gbuf);
  seg_softmax<<<dim3(256, B_), 256, 0, stream>>>(fbuf, gbuf, segst, y_ws);
  gemm_hy<<<256, 256, 0, stream>>>(y_ws, Whb, bhb, hy_ws);
  gather_out<<<16384, 256, 0, stream>>>(hy_ws, jx, d_out, flag);
}

// Round 8
// 392.657 us; speedup vs baseline: 1.0923x; 1.0621x over previous
//
#include <hip/hip_runtime.h>
#include <stdint.h>

#define B_ 4
#define N_ 16384
#define D_ 512
#define S_ 512

typedef __attribute__((ext_vector_type(8))) short bf16x8;
typedef __attribute__((ext_vector_type(4))) float f32x4;

__device__ __forceinline__ float bf2f(unsigned short u) {
  union { unsigned int i; float f; } v; v.i = ((unsigned int)u) << 16; return v.f;
}
__device__ __forceinline__ unsigned short f2bf(float f) {
  unsigned int x = __float_as_uint(f);
  return (unsigned short)((x + 0x7FFFu + ((x >> 16) & 1u)) >> 16);
}
__device__ __forceinline__ float ldf(const void* p, long i, bool f32) {
  return f32 ? ((const float*)p)[i] : bf2f(((const unsigned short*)p)[i]);
}
__device__ __forceinline__ void gl_lds16(void* lds_base, const void* g) {
  __builtin_amdgcn_global_load_lds(
      (const __attribute__((address_space(1))) unsigned int*)g,
      (__attribute__((address_space(3))) unsigned int*)lds_base,
      16, 0, 0);
}

__device__ __forceinline__ bool jx_is_i64(const int* jx32) { return jx32[N_ - 1] == 0; }
__device__ __forceinline__ int seg_id(const int* jx32, int n, bool i64) {
  return i64 ? jx32[2 * n] : jx32[n];
}

// Per-block dtype classify (true = x is f32); see round-2 notes.
__device__ __forceinline__ bool classify_f32(const unsigned short* x, int* cnt) {
  int c = 0;
#pragma unroll
  for (int i = 0; i < 8; i++) {
    unsigned short w = x[threadIdx.x * 8 + i];
    int e = (w >> 7) & 0xFF;
    if (e == 0 || (e >= 100 && e <= 140)) c++;
  }
  cnt[threadIdx.x] = c;
  __syncthreads();
  for (int s = 128; s > 0; s >>= 1) {
    if ((int)threadIdx.x < s) cnt[threadIdx.x] += cnt[threadIdx.x + s];
    __syncthreads();
  }
  bool f32 = cnt[0] < 1843;
  __syncthreads();
  return f32;
}

// ---------------------------------------------------------------------------
// prep_all: [0,16384) x -> xb bf16; [16384,19462) weights/biases;
// [19462,19465) segment bounds + publish flag for gather_out.
__global__ __launch_bounds__(256)
void prep_all(const void* __restrict__ x, const int* __restrict__ jx,
              const void* __restrict__ Wf, const void* __restrict__ bfv,
              const void* __restrict__ Wg, const void* __restrict__ bgv,
              const void* __restrict__ Wh, const void* __restrict__ bhv,
              unsigned short* __restrict__ xb, unsigned short* __restrict__ Wfg,
              unsigned short* __restrict__ biasfg, unsigned short* __restrict__ Whb,
              unsigned short* __restrict__ bhb, int* __restrict__ segst,
              int* __restrict__ flag) {
  const int blk = blockIdx.x, tid = threadIdx.x;
  __shared__ int cnt[256];
  const bool f32 = classify_f32((const unsigned short*)x, cnt);
  if (blk >= 19462) {  // bounds + flag
    if (blk == 19462 && tid == 0) flag[0] = f32 ? 1 : 0;
    int s = (blk - 19462) * 256 + tid;
    if (s > S_) return;
    bool i64 = jx_is_i64(jx);
    int lo = 0, hi = N_;
    while (lo < hi) {
      int mid = (lo + hi) >> 1;
      if (seg_id(jx, mid, i64) < s) lo = mid + 1; else hi = mid;
    }
    segst[s] = lo;
    return;
  }
  if (blk < 16384) {  // x -> bf16
    const size_t i0 = ((size_t)blk * 256 + tid) * 8;
    bf16x8 v;
    if (f32) {
      const float4* p = (const float4*)((const float*)x + i0);
      float4 a = p[0], b = p[1];
      v[0]=f2bf(a.x); v[1]=f2bf(a.y); v[2]=f2bf(a.z); v[3]=f2bf(a.w);
      v[4]=f2bf(b.x); v[5]=f2bf(b.y); v[6]=f2bf(b.z); v[7]=f2bf(b.w);
    } else {
      v = *(const bf16x8*)((const unsigned short*)x + i0);
    }
    *(bf16x8*)(xb + i0) = v;
  } else {  // weights / biases
    int idx = (blk - 16384) * 256 + tid;
    if (idx < 524288) {
      int e = idx >> 9, d = idx & 511;
      float v = (e < 512) ? ldf(Wf, (long)e * 512 + d, f32)
                          : ldf(Wg, (long)(e - 512) * 512 + d, f32);
      Wfg[idx] = f2bf(v);
    } else if (idx < 786432) {
      Whb[idx - 524288] = f2bf(ldf(Wh, idx - 524288, f32));
    } else if (idx < 787456) {
      int j = idx - 786432;
      biasfg[j] = f2bf(j < 512 ? ldf(bfv, j, f32) : ldf(bgv, j - 512, f32));
    } else if (idx < 787968) {
      bhb[idx - 787456] = f2bf(ldf(bhv, idx - 787456, f32));
    }
  }
}

// ---------------------------------------------------------------------------
// fg GEMM (R3-proven): C[m,e]=sum_k xb[m,k]*Wfg[e,k]+bias[e]; all bf16;
// 128x128 tile, BK=32, global_load_lds w16, 4 waves 2x2, 4x4 mfma 16x16x32.
// XCD swizzle so the 8 col-tiles sharing an A row-tile run on one XCD's L2.
#define BK 32

__global__ __launch_bounds__(256, 2)
void gemm_fg(const unsigned short* __restrict__ A, const unsigned short* __restrict__ Bm,
             const unsigned short* __restrict__ bias,
             unsigned short* __restrict__ Cf, unsigned short* __restrict__ Cg) {
  __shared__ __align__(16) unsigned short As[128 * BK];
  __shared__ __align__(16) unsigned short Bs[128 * BK];
  const int L = blockIdx.x;
  const int xcd = L & 7, local = L >> 3;
  const int tm = xcd * 64 + local / 8;     // tilesM=512 -> 64 per XCD
  const int tn = local % 8;
  const int m0 = tm * 128, n0 = tn * 128;

  const int tid  = threadIdx.x;
  const int w    = tid >> 6;
  const int lane = tid & 63;
  const int wm   = w >> 1, wn = w & 1;
  const int l15  = lane & 15, l4 = lane >> 4;
  const int srow = lane >> 2;
  const int scol = (lane & 3) * 8;

  f32x4 acc[4][4];
#pragma unroll
  for (int i = 0; i < 4; i++)
#pragma unroll
    for (int j = 0; j < 4; j++) acc[i][j] = (f32x4){0.f, 0.f, 0.f, 0.f};

  for (int kt = 0; kt < 512; kt += BK) {
    __syncthreads();
#pragma unroll
    for (int r = 0; r < 2; r++) {
      const int rb = (r * 4 + w) * 16;
      gl_lds16(&As[rb * BK], A + (size_t)(m0 + rb + srow) * 512 + kt + scol);
      gl_lds16(&Bs[rb * BK], Bm + (size_t)(n0 + rb + srow) * 512 + kt + scol);
    }
    __syncthreads();

    bf16x8 a[4], bb[4];
#pragma unroll
    for (int i = 0; i < 4; i++)
      a[i] = *(const bf16x8*)&As[(wm * 64 + i * 16 + l15) * BK + l4 * 8];
#pragma unroll
    for (int j = 0; j < 4; j++)
      bb[j] = *(const bf16x8*)&Bs[(wn * 64 + j * 16 + l15) * BK + l4 * 8];
#pragma unroll
    for (int i = 0; i < 4; i++)
#pragma unroll
      for (int j = 0; j < 4; j++)
        acc[i][j] = __builtin_amdgcn_mfma_f32_16x16x32_bf16(a[i], bb[j], acc[i][j], 0, 0, 0);
  }

  // epilogue: C/D layout col=lane&15, row=(lane>>4)*4+r; split f (col<512) / g
#pragma unroll
  for (int j = 0; j < 4; j++) {
    const int col = n0 + wn * 64 + j * 16 + l15;
    const float bv = bf2f(bias[col]);
    unsigned short* base = (col < 512) ? Cf : Cg;
    const int cc = col & 511;
#pragma unroll
    for (int i = 0; i < 4; i++) {
      const int rowb = m0 + wm * 64 + i * 16 + l4 * 4;
#pragma unroll
      for (int r = 0; r < 4; r++)
        base[(size_t)(rowb + r) * 512 + cc] = f2bf(acc[i][j][r] + bv);
    }
  }
}

// ---------------------------------------------------------------------------
// Online segment softmax + weighted sum; 2 segments/block, 4 cols/thread,
// n-loop unrolled by 2 for load ILP. |g| < ~7 so no max subtraction.
__global__ __launch_bounds__(256)
void seg_softmax(const unsigned short* __restrict__ f, const unsigned short* __restrict__ g,
                 const int* __restrict__ segst, unsigned short* __restrict__ y) {
  const int s = blockIdx.x * 2 + (threadIdx.x >> 7);
  const int b = blockIdx.y;
  const int d0 = (threadIdx.x & 127) * 4;
  const int st = segst[s], en = segst[s + 1];
  float den0=0.f, den1=0.f, den2=0.f, den3=0.f;
  float y0=0.f, y1=0.f, y2=0.f, y3=0.f;
  int n = st;
  for (; n + 1 < en; n += 2) {
    const size_t offA = (size_t)(b * N_ + n) * 512 + d0;
    const size_t offB = offA + 512;
    const uint2 fpA = *(const uint2*)(f + offA);
    const uint2 gpA = *(const uint2*)(g + offA);
    const uint2 fpB = *(const uint2*)(f + offB);
    const uint2 gpB = *(const uint2*)(g + offB);
    {
      const float f0 = bf2f((unsigned short)fpA.x), f1 = bf2f((unsigned short)(fpA.x >> 16));
      const float f2 = bf2f((unsigned short)fpA.y), f3 = bf2f((unsigned short)(fpA.y >> 16));
      const float g0 = bf2f((unsigned short)gpA.x), g1 = bf2f((unsigned short)(gpA.x >> 16));
      const float g2 = bf2f((unsigned short)gpA.y), g3 = bf2f((unsigned short)(gpA.y >> 16));
      const float e0 = __expf(g0), e1 = __expf(g1), e2 = __expf(g2), e3 = __expf(g3);
      den0 += e0; den1 += e1; den2 += e2; den3 += e3;
      y0 += f0 * e0; y1 += f1 * e1; y2 += f2 * e2; y3 += f3 * e3;
    }
    {
      const float f0 = bf2f((unsigned short)fpB.x), f1 = bf2f((unsigned short)(fpB.x >> 16));
      const float f2 = bf2f((unsigned short)fpB.y), f3 = bf2f((unsigned short)(fpB.y >> 16));
      const float g0 = bf2f((unsigned short)gpB.x), g1 = bf2f((unsigned short)(gpB.x >> 16));
      const float g2 = bf2f((unsigned short)gpB.y), g3 = bf2f((unsigned short)(gpB.y >> 16));
      const float e0 = __expf(g0), e1 = __expf(g1), e2 = __expf(g2), e3 = __expf(g3);
      den0 += e0; den1 += e1; den2 += e2; den3 += e3;
      y0 += f0 * e0; y1 += f1 * e1; y2 += f2 * e2; y3 += f3 * e3;
    }
  }
  if (n < en) {
    const size_t off = (size_t)(b * N_ + n) * 512 + d0;
    const uint2 fp = *(const uint2*)(f + off);
    const uint2 gp = *(const uint2*)(g + off);
    const float f0 = bf2f((unsigned short)fp.x), f1 = bf2f((unsigned short)(fp.x >> 16));
    const float f2 = bf2f((unsigned short)fp.y), f3 = bf2f((unsigned short)(fp.y >> 16));
    const float g0 = bf2f((unsigned short)gp.x), g1 = bf2f((unsigned short)(gp.x >> 16));
    const float g2 = bf2f((unsigned short)gp.y), g3 = bf2f((unsigned short)(gp.y >> 16));
    const float e0 = __expf(g0), e1 = __expf(g1), e2 = __expf(g2), e3 = __expf(g3);
    den0 += e0; den1 += e1; den2 += e2; den3 += e3;
    y0 += f0 * e0; y1 += f1 * e1; y2 += f2 * e2; y3 += f3 * e3;
  }
  uint2 o;
  if (en > st) {
    o.x = (unsigned int)f2bf(y0 / den0) | ((unsigned int)f2bf(y1 / den1) << 16);
    o.y = (unsigned int)f2bf(y2 / den2) | ((unsigned int)f2bf(y3 / den3) << 16);
  } else { o.x = 0u; o.y = 0u; }
  *(uint2*)(y + (size_t)(b * S_ + s) * 512 + d0) = o;
}

// ---------------------------------------------------------------------------
// hy GEMM: hy[m,c] = sum_k y[m,k]*Whb[c,k] + bhb[c]; 64x64 tiles, 256 blocks.
__global__ __launch_bounds__(256)
void gemm_hy(const unsigned short* __restrict__ y, const unsigned short* __restrict__ Whb,
             const unsigned short* __restrict__ bhb, unsigned short* __restrict__ hy) {
  __shared__ __align__(16) unsigned short As[64 * 32];
  __shared__ __align__(16) unsigned short Bs[64 * 32];
  const int tid = threadIdx.x;
  const int w = tid >> 6, lane = tid & 63;
  const int l15 = lane & 15, l4 = lane >> 4;
  const int m0 = (blockIdx.x >> 3) * 64, c0 = (blockIdx.x & 7) * 64;
  const int srow = lane >> 2, scol = (lane & 3) * 8;

  f32x4 acc[4];
#pragma unroll
  for (int j = 0; j < 4; j++) acc[j] = (f32x4){0.f, 0.f, 0.f, 0.f};

  for (int kt = 0; kt < 512; kt += 32) {
    __syncthreads();
    gl_lds16(&As[(w * 16) * 32], y   + (size_t)(m0 + w * 16 + srow) * 512 + kt + scol);
    gl_lds16(&Bs[(w * 16) * 32], Whb + (size_t)(c0 + w * 16 + srow) * 512 + kt + scol);
    __syncthreads();
    bf16x8 a = *(const bf16x8*)&As[(w * 16 + l15) * 32 + l4 * 8];
#pragma unroll
    for (int j = 0; j < 4; j++) {
      bf16x8 bb = *(const bf16x8*)&Bs[(j * 16 + l15) * 32 + l4 * 8];
      acc[j] = __builtin_amdgcn_mfma_f32_16x16x32_bf16(a, bb, acc[j], 0, 0, 0);
    }
  }
#pragma unroll
  for (int j = 0; j < 4; j++) {
    const float bv = bf2f(bhb[c0 + j * 16 + l15]);
#pragma unroll
    for (int r = 0; r < 4; r++)
      hy[(size_t)(m0 + w * 16 + l4 * 4 + r) * 512 + c0 + j * 16 + l15] =
          f2bf(acc[j][r] + bv);
  }
}

// ---------------------------------------------------------------------------
// out[b,n,:] = hy[b*S + jx[n], :]; one wave per row, vectorized stores.
__global__ __launch_bounds__(256)
void gather_out(const unsigned short* __restrict__ hy, const int* __restrict__ jx,
                void* __restrict__ out, const int* __restrict__ flag) {
  const bool f32 = flag[0] != 0;
  const int gid  = blockIdx.x * 256 + threadIdx.x;
  const int wid  = gid >> 6;
  const int lane = gid & 63;
  const int b = wid >> 14;
  const int n = wid & (N_ - 1);
  const bool i64 = jx_is_i64(jx);
  const int s = seg_id(jx, n, i64);
  const bf16x8 v = *(const bf16x8*)(hy + (size_t)(b * S_ + s) * 512 + lane * 8);
  if (f32) {
    float* dst = (float*)out + (size_t)wid * 512 + lane * 8;
    float4 lo, hi;
    lo.x=bf2f((unsigned short)v[0]); lo.y=bf2f((unsigned short)v[1]);
    lo.z=bf2f((unsigned short)v[2]); lo.w=bf2f((unsigned short)v[3]);
    hi.x=bf2f((unsigned short)v[4]); hi.y=bf2f((unsigned short)v[5]);
    hi.z=bf2f((unsigned short)v[6]); hi.w=bf2f((unsigned short)v[7]);
    *(float4*)dst = lo;
    *(float4*)(dst + 4) = hi;
  } else {
    *(bf16x8*)((unsigned short*)out + (size_t)wid * 512 + lane * 8) = v;
  }
}

// ---------------------------------------------------------------------------
extern "C" void kernel_launch(void* const* d_in, const int* in_sizes, int n_in,
                              void* d_out, int out_size, void* d_ws, size_t ws_size,
                              hipStream_t stream) {
  const void* x  = d_in[0];
  const int* jx  = (const int*)d_in[1];
  const void* Wf = d_in[3];
  const void* bf = d_in[4];
  const void* Wg = d_in[5];
  const void* bg = d_in[6];
  const void* Wh = d_in[7];
  const void* bh = d_in[8];

  // EXACT R3-proven ws layout (ends at 72.4 MB; R5 showed 80.8 MB is OOB).
  char* ws = (char*)d_ws;
  int* flag              = (int*)(ws + 0);
  int* segst             = (int*)(ws + 4096);
  unsigned short* biasfg = (unsigned short*)(ws + 8192);
  unsigned short* bhb    = (unsigned short*)(ws + 16384);
  unsigned short* Wfg    = (unsigned short*)(ws + 32768);      // 1 MB
  unsigned short* Whb    = (unsigned short*)(ws + 1081344);    // 0.5 MB
  unsigned short* y_ws   = (unsigned short*)(ws + 1605632);    // 2 MB
  unsigned short* hy_ws  = (unsigned short*)(ws + 3702784);    // 2 MB
  unsigned short* xb     = (unsigned short*)(ws + 8388608);    // 64 MB bf16 x
  // f/g (2 x 64 MB bf16) live in d_out (128 MB f32); dead before gather.
  unsigned short* fbuf   = (unsigned short*)d_out;
  unsigned short* gbuf   = (unsigned short*)d_out + (size_t)B_ * N_ * D_;

  prep_all<<<19465, 256, 0, stream>>>(x, jx, Wf, bf, Wg, bg, Wh, bh,
                                      xb, Wfg, biasfg, Whb, bhb, segst, flag);
  gemm_fg<<<4096, 256, 0, stream>>>(xb, Wfg, biasfg, fbuf, gbuf);
  seg_softmax<<<dim3(256, B_), 256, 0, stream>>>(fbuf, gbuf, segst, y_ws);
  gemm_hy<<<256, 256, 0, stream>>>(y_ws, Whb, bhb, hy_ws);
  gather_out<<<16384, 256, 0, stream>>>(hy_ws, jx, d_out, flag);
}